// Round 2
// baseline (247.197 us; speedup 1.0000x reference)
//
#include <hip/hip_runtime.h>
#include <cstdint>

// Problem: out = inputs @ W  (softmax over a constant axis is uniform; GAT collapses to the GEMM)
// inputs: (131072, 256) fp32, W: (256,256) fp32, out: (131072, 256) fp32.
//
// Strategy (R2): W fits in LDS entirely as bf16 (128 KB). One cooperative stage +
// ONE barrier, then a barrier-free main loop: A streams global->reg->bf16 frags,
// B-frags come from LDS, 16 waves/CU each self-paced on vmcnt. This removes the
// R1 bottleneck (4-iteration K-loop with per-iter block-wide barrier drains ->
// latency-bound at 30% HBM).

static constexpr int MTOT = 64 * 2048;   // 131072
static constexpr int KDIM = 256;
static constexpr int NDIM = 256;

typedef __bf16 bf16x8 __attribute__((ext_vector_type(8)));
typedef float f32x4 __attribute__((ext_vector_type(4)));

__device__ __forceinline__ uint32_t f2bf_pk(float a, float b) {
    // pack two fp32 -> two bf16 (RNE), lo = a, hi = b
    uint32_t ua = __float_as_uint(a);
    uint32_t ub = __float_as_uint(b);
    ua = ua + 0x7fffu + ((ua >> 16) & 1u);
    ub = ub + 0x7fffu + ((ub >> 16) & 1u);
    return (ua >> 16) | (ub & 0xffff0000u);
}

// --- kernel 1: W (k-major fp32) -> bf16 LDS-image in workspace --------------
// Image layout: 16-byte unit u = koct*256 + n  (koct = k/8, n = column),
// holding 8 k-consecutive bf16 of column n. This is exactly what the main
// kernel's B-fragment reads want: frag(n, k0=ks*32+quad*8) = unit (k0/8, n).
__global__ void wt_image(const float* __restrict__ W, unsigned short* __restrict__ img) {
    int k = blockIdx.x;    // 256 blocks
    int n = threadIdx.x;   // 256 threads (coalesced read of row k)
    float v = W[k * NDIM + n];
    uint32_t u = __float_as_uint(v);
    u = u + 0x7fffu + ((u >> 16) & 1u);
    img[((size_t)((k >> 3) * NDIM + n) << 3) + (k & 7)] = (unsigned short)(u >> 16);
}

// --- kernel 2: main GEMM -----------------------------------------------------
// 1024 threads = 16 waves. Wave w computes rows [blk*256 + w*16, +16) x all 256 cols.
// Per k-step (K=32, 8 steps): A-frag = 8 consecutive fp32 from the lane's row
// (verified 16x16x32 layout: A[m=lane&15][k=(lane>>4)*8+j]), converted to bf16;
// 16 N-tiles: ds_read_b128 B-frag + mfma_f32_16x16x32_bf16.
__global__ __launch_bounds__(1024)
void gat_gemm(const float* __restrict__ A, const uint4* __restrict__ img,
              float* __restrict__ C) {
    __shared__ uint4 Bs[8192];   // 128 KB, identical linear layout to img

    const int tid = threadIdx.x;

    // ---- stage whole W image into LDS (coalesced dwordx4, once) ----
#pragma unroll
    for (int i = 0; i < 8; ++i)
        Bs[tid + i * 1024] = img[tid + i * 1024];

    const int lane = tid & 63;
    const int wave = tid >> 6;
    const int l15  = lane & 15;
    const int quad = lane >> 4;

    const int row = blockIdx.x * 256 + wave * 16 + l15;
    const float* arow = A + (size_t)row * KDIM;   // lane's A row

    f32x4 acc[16];
#pragma unroll
    for (int j = 0; j < 16; ++j) acc[j] = (f32x4)0.0f;

    __syncthreads();   // the ONLY barrier

    // software pipeline: prefetch k-step 0
    float4 a0 = *(const float4*)(arow + quad * 8);
    float4 a1 = *(const float4*)(arow + quad * 8 + 4);

#pragma unroll
    for (int ks = 0; ks < 8; ++ks) {
        float4 n0, n1;
        if (ks < 7) {
            const float* p = arow + (ks + 1) * 32 + quad * 8;
            n0 = *(const float4*)(p);
            n1 = *(const float4*)(p + 4);
        }

        // convert current A to bf16 fragment
        uint4 ap;
        ap.x = f2bf_pk(a0.x, a0.y); ap.y = f2bf_pk(a0.z, a0.w);
        ap.z = f2bf_pk(a1.x, a1.y); ap.w = f2bf_pk(a1.z, a1.w);
        bf16x8 af = __builtin_bit_cast(bf16x8, ap);

        // B-frags: unit base (ks*4 + quad)*256 + l15, stepping n-tiles by 16 units
        const uint4* bbase = &Bs[(ks * 4 + quad) * 256 + l15];
#pragma unroll
        for (int j = 0; j < 16; ++j) {
            bf16x8 bf = __builtin_bit_cast(bf16x8, bbase[j * 16]);
            acc[j] = __builtin_amdgcn_mfma_f32_16x16x32_bf16(af, bf, acc[j], 0, 0, 0);
        }

        a0 = n0; a1 = n1;
    }

    // ---- epilogue: C/D layout col=lane&15, row=(lane>>4)*4+r (verified R1) ----
    const size_t rbase = (size_t)(blockIdx.x * 256 + wave * 16 + quad * 4);
#pragma unroll
    for (int j = 0; j < 16; ++j) {
        const int n = j * 16 + l15;
#pragma unroll
        for (int r = 0; r < 4; ++r)
            C[(rbase + r) * NDIM + n] = acc[j][r];
    }
}

extern "C" void kernel_launch(void* const* d_in, const int* in_sizes, int n_in,
                              void* d_out, int out_size, void* d_ws, size_t ws_size,
                              hipStream_t stream) {
    (void)in_sizes; (void)n_in; (void)out_size; (void)ws_size;
    const float* inputs = (const float*)d_in[0];
    const float* W      = (const float*)d_in[1];
    // d_in[2] ('a') is mathematically unused: softmax over a constant axis is uniform,
    // so the output is exactly inputs @ W.
    unsigned short* img = (unsigned short*)d_ws;     // 128 KB scratch
    float* out = (float*)d_out;

    hipLaunchKernelGGL(wt_image, dim3(KDIM), dim3(NDIM), 0, stream, W, img);
    hipLaunchKernelGGL(gat_gemm, dim3(MTOT / 256), dim3(1024), 0, stream,
                       inputs, (const uint4*)img, out);
}